// Round 1
// baseline (4161.869 us; speedup 1.0000x reference)
//
#include <hip/hip_runtime.h>

#define NN 50000      // nodes
#define NE 800000     // edges
#define NGR 16        // graphs

typedef unsigned short u16;
typedef unsigned int u32;
typedef __attribute__((ext_vector_type(8))) short bf16x8;
typedef __attribute__((ext_vector_type(4))) float f32x4;

__device__ __forceinline__ u16 f2bf(float f) {       // RNE f32->bf16
  u32 u = __float_as_uint(f);
  return (u16)((u + 0x7fffu + ((u >> 16) & 1u)) >> 16);
}

// ---------- degree histogram ----------
__global__ void hist_deg(const int* col, int* deg) {
  int e = blockIdx.x * blockDim.x + threadIdx.x;
  if (e < NE) atomicAdd(&deg[col[e]], 1);
}

// ---------- per-graph counts (sorted ids) ----------
__device__ int lbound(const int* a, int n, int v) {
  int lo = 0, hi = n;
  while (lo < hi) { int m = (lo + hi) >> 1; if (a[m] < v) lo = m + 1; else hi = m; }
  return lo;
}
__global__ void count_graphs(const int* batch, const int* ebatch, int* cnt_n, int* cnt_e) {
  int t = threadIdx.x;
  if (t < NGR) cnt_n[t] = lbound(batch, NN, t + 1) - lbound(batch, NN, t);
  else if (t < 2 * NGR) { int g = t - NGR; cnt_e[g] = lbound(ebatch, NE, g + 1) - lbound(ebatch, NE, g); }
}

// ---------- exclusive scan of deg -> csr_off (single block) ----------
__global__ __launch_bounds__(256) void scan_deg(const int* deg, int* off) {
  __shared__ int sums[256];
  const int CH = (NN + 255) / 256;
  int t = threadIdx.x;
  int base = t * CH;
  int s = 0;
  for (int i = 0; i < CH; i++) { int idx = base + i; if (idx < NN) s += deg[idx]; }
  sums[t] = s;
  __syncthreads();
  for (int d = 1; d < 256; d <<= 1) {
    int v = (t >= d) ? sums[t - d] : 0;
    __syncthreads();
    sums[t] += v;
    __syncthreads();
  }
  int run = (t == 0) ? 0 : sums[t - 1];
  for (int i = 0; i < CH; i++) { int idx = base + i; if (idx < NN) { off[idx] = run; run += deg[idx]; } }
  if (t == 255) off[NN] = run;
}

// ---------- CSR fill ----------
__global__ void fill_csr(const int* col, const int* off, int* cursor, int* eid) {
  int e = blockIdx.x * blockDim.x + threadIdx.x;
  if (e < NE) {
    int c = col[e];
    int p = atomicAdd(&cursor[c], 1);
    eid[off[c] + p] = e;
  }
}

// ---------- weights f32 -> bf16 TRANSPOSED (W1T[l][n][k], W2T[l][n][k]) ----------
__global__ void prep_w_k(const float* W1, const float* W2, u16* W1T, u16* W2T) {
  int i = blockIdx.x * 256 + threadIdx.x;
  if (i < 3 * 128 * 128) {
    int l = i / 16384, k = (i >> 7) & 127, n = i & 127;
    W1T[l * 16384 + n * 128 + k] = f2bf(W1[i]);
  } else {
    int j = i - 3 * 128 * 128;
    if (j < 3 * 128 * 64) {
      int l = j / 8192, k = (j >> 6) & 127, n = j & 63;
      W2T[l * 8192 + n * 128 + k] = f2bf(W2[j]);
    }
  }
}

// ---------- layer-0 pool: ea rows [NE,64] by sorted ebatch -> gacc[g*256 + loff + d] ----------
// float4 per lane (16B), 4 row-slots per wave, per-slot run tracking of graph id.
__global__ __launch_bounds__(256) void pool_edges_k(const float* ea, const int* ebatch,
                                                    float* gacc, int loff) {
  int gid = blockIdx.x * blockDim.x + threadIdx.x;
  int w = gid >> 6, lane = gid & 63;
  const int NW = (gridDim.x * blockDim.x) >> 6;
  const int CH = (((NE / 4) + NW - 1) / NW) * 4;     // rows per wave, multiple of 4
  int r0 = w * CH, r1 = min(r0 + CH, NE);
  if (r0 >= r1) return;
  int q = lane >> 4;          // row slot 0..3
  int c4 = (lane & 15) * 4;   // column base
  float4 acc = {0.f, 0.f, 0.f, 0.f};
  int cg = ebatch[r0 + q];
  for (int r = r0; r < r1; r += 4) {
    int rr = r + q;           // r1,r0 multiples of 4 -> rr < r1 <= NE
    int g = ebatch[rr];
    if (g != cg) {
      float* dst = gacc + cg * 256 + loff + c4;
      atomicAdd(dst + 0, acc.x); atomicAdd(dst + 1, acc.y);
      atomicAdd(dst + 2, acc.z); atomicAdd(dst + 3, acc.w);
      acc = {0.f, 0.f, 0.f, 0.f};
      cg = g;
    }
    float4 v = *(const float4*)(ea + (size_t)rr * 64 + c4);
    acc.x += v.x; acc.y += v.y; acc.z += v.z; acc.w += v.w;
  }
  float* dst = gacc + cg * 256 + loff + c4;
  atomicAdd(dst + 0, acc.x); atomicAdd(dst + 1, acc.y);
  atomicAdd(dst + 2, acc.z); atomicAdd(dst + 3, acc.w);
}

// ---------- h = CSR gather-mean of ea; pool h by batch -> gacc[g*256+loff+d] ----------
// float4 per lane; 4 edge-slots per wave; shuffle-reduce across slots.
__global__ __launch_bounds__(256) void gather_k(const float* ea, const int* off, const int* eid,
                                                const int* batch, float* hbuf, float* gacc,
                                                int loff, int store_h) {
  int gid = blockIdx.x * blockDim.x + threadIdx.x;
  int w = gid >> 6, lane = gid & 63;
  int nw = (gridDim.x * blockDim.x) >> 6;
  int q = lane >> 4;          // edge slot 0..3
  int c4 = (lane & 15) * 4;   // column base
  for (int n = w; n < NN; n += nw) {
    int s = off[n], e = off[n + 1];
    float4 acc = {0.f, 0.f, 0.f, 0.f};
    for (int i = s + q; i < e; i += 4) {
      float4 v = *(const float4*)(ea + (size_t)eid[i] * 64 + c4);
      acc.x += v.x; acc.y += v.y; acc.z += v.z; acc.w += v.w;
    }
    acc.x += __shfl_xor(acc.x, 16); acc.x += __shfl_xor(acc.x, 32);
    acc.y += __shfl_xor(acc.y, 16); acc.y += __shfl_xor(acc.y, 32);
    acc.z += __shfl_xor(acc.z, 16); acc.z += __shfl_xor(acc.z, 32);
    acc.w += __shfl_xor(acc.w, 16); acc.w += __shfl_xor(acc.w, 32);
    if (q == 0) {
      float inv = 1.f / (float)max(e - s, 1);
      float4 hv = {acc.x * inv, acc.y * inv, acc.z * inv, acc.w * inv};
      if (store_h) *(float4*)(hbuf + (size_t)n * 64 + c4) = hv;
      float* dst = gacc + batch[n] * 256 + loff + c4;
      atomicAdd(dst + 0, hv.x); atomicAdd(dst + 1, hv.y);
      atomicAdd(dst + 2, hv.z); atomicAdd(dst + 3, hv.w);
    }
  }
}

// ---------- edge MLP via bf16 MFMA: ea = relu([h[row],ea]@W1+b1)@W2+b2, in-place ----------
// Block = 256 thr (4 waves), 64 edges. Fused ge-pool epilogue (ebatch sorted ->
// block is single-graph except <=15 boundary blocks).
__global__ __launch_bounds__(256) void mlp_mfma_k(
    const float* hbuf, float* ea, const int* rowp,
    const u16* W1T, const float* b1,     // W1T [128n][128k] bf16
    const u16* W2T, const float* b2,     // W2T [64n][128k] bf16
    const int* ebatch, float* gacc, int loff) {
  __shared__ u16 sh[2 * 64 * 136];       // xin | hid
  u16* xin = sh;
  u16* hid = sh + 64 * 136;
  const int t = threadIdx.x;
  const int e0 = blockIdx.x * 64;
  const int lane = t & 63;
  const int wave = t >> 6;
  const int m16 = lane & 15;             // fragment row/col index
  const int quad = lane >> 4;            // k-subblock

  // ---- preload B fragments (registers, straight from global; L2-hot) ----
  bf16x8 B1[2][4], B2[4];
#pragma unroll
  for (int ni = 0; ni < 2; ni++)
#pragma unroll
    for (int ki = 0; ki < 4; ki++)
      B1[ni][ki] = *(const bf16x8*)(W1T + (wave * 32 + ni * 16 + m16) * 128 + ki * 32 + quad * 8);
#pragma unroll
  for (int ki = 0; ki < 4; ki++)
    B2[ki] = *(const bf16x8*)(W2T + (wave * 16 + m16) * 128 + ki * 32 + quad * 8);

  // ---- stage xin[64][128] = [h[row[e]], ea[e]] as bf16 ----
#pragma unroll
  for (int it = 0; it < 8; it++) {
    int f = it * 256 + t;                // float4 id 0..2047
    int r = f >> 5;                      // edge row 0..63
    int c = (f & 31) * 4;                // col 0..124
    const float* src;
    if (c < 64) {
      int nd = rowp[e0 + r];
      src = hbuf + (size_t)nd * 64 + c;
    } else {
      src = ea + (size_t)(e0 + r) * 64 + (c - 64);
    }
    float4 v = *(const float4*)src;
    u32 p0 = (u32)f2bf(v.x) | ((u32)f2bf(v.y) << 16);
    u32 p1 = (u32)f2bf(v.z) | ((u32)f2bf(v.w) << 16);
    u32* dst = (u32*)&xin[r * 136 + c];
    dst[0] = p0;
    dst[1] = p1;
  }
  __syncthreads();

  // ---- GEMM1: [64x128] @ W1[128x128] -> hid, +bias, ReLU ----
  f32x4 zero = {0.f, 0.f, 0.f, 0.f};
  f32x4 acc1[2][4];
#pragma unroll
  for (int ni = 0; ni < 2; ni++)
#pragma unroll
    for (int mi = 0; mi < 4; mi++) acc1[ni][mi] = zero;

#pragma unroll
  for (int ki = 0; ki < 4; ki++) {
#pragma unroll
    for (int mi = 0; mi < 4; mi++) {
      bf16x8 A = *(const bf16x8*)&xin[(mi * 16 + m16) * 136 + ki * 32 + quad * 8];
      acc1[0][mi] = __builtin_amdgcn_mfma_f32_16x16x32_bf16(A, B1[0][ki], acc1[0][mi], 0, 0, 0);
      acc1[1][mi] = __builtin_amdgcn_mfma_f32_16x16x32_bf16(A, B1[1][ki], acc1[1][mi], 0, 0, 0);
    }
  }
  float b1v0 = b1[wave * 32 + m16];
  float b1v1 = b1[wave * 32 + 16 + m16];
#pragma unroll
  for (int mi = 0; mi < 4; mi++) {
#pragma unroll
    for (int reg = 0; reg < 4; reg++) {
      int r = mi * 16 + quad * 4 + reg;
      hid[r * 136 + wave * 32 + m16]      = f2bf(fmaxf(acc1[0][mi][reg] + b1v0, 0.f));
      hid[r * 136 + wave * 32 + 16 + m16] = f2bf(fmaxf(acc1[1][mi][reg] + b1v1, 0.f));
    }
  }
  __syncthreads();

  // ---- GEMM2: hid[64x128] @ W2[128x64] -> ea rows (in-place), +bias ----
  f32x4 acc2[4];
#pragma unroll
  for (int mi = 0; mi < 4; mi++) acc2[mi] = zero;
#pragma unroll
  for (int ki = 0; ki < 4; ki++) {
#pragma unroll
    for (int mi = 0; mi < 4; mi++) {
      bf16x8 A = *(const bf16x8*)&hid[(mi * 16 + m16) * 136 + ki * 32 + quad * 8];
      acc2[mi] = __builtin_amdgcn_mfma_f32_16x16x32_bf16(A, B2[ki], acc2[mi], 0, 0, 0);
    }
  }
  float b2v = b2[wave * 16 + m16];
#pragma unroll
  for (int mi = 0; mi < 4; mi++) {
#pragma unroll
    for (int reg = 0; reg < 4; reg++) {
      int r = mi * 16 + quad * 4 + reg;
      ea[(size_t)(e0 + r) * 64 + wave * 16 + m16] = acc2[mi][reg] + b2v;
    }
  }

  // ---- fused ge pooling: sum this block's 64 output rows per graph ----
  int g0 = ebatch[e0], g1 = ebatch[e0 + 63];
  int colo = wave * 16 + m16;
  if (g0 == g1) {                        // fast path: single-graph block
    float s = 0.f;
#pragma unroll
    for (int mi = 0; mi < 4; mi++)
#pragma unroll
      for (int reg = 0; reg < 4; reg++) s += acc2[mi][reg] + b2v;
    s += __shfl_xor(s, 16);
    s += __shfl_xor(s, 32);
    if (quad == 0) atomicAdd(&gacc[g0 * 256 + loff + colo], s);
  } else {                               // boundary block (<=15 total): per-value atomics
#pragma unroll
    for (int mi = 0; mi < 4; mi++)
#pragma unroll
      for (int reg = 0; reg < 4; reg++) {
        int r = mi * 16 + quad * 4 + reg;
        atomicAdd(&gacc[ebatch[e0 + r] * 256 + loff + colo], acc2[mi][reg] + b2v);
      }
  }
}

// ---------- finalize: means (acc already in output layout), head, f32 out ----------
__global__ __launch_bounds__(256) void finalize_k(
    const float* gn_acc, const float* ge_acc,
    const int* cnt_n, const int* cnt_e,
    const float* Wo1, const float* bo1,
    const float* Wo2, const float* bo2,
    const float* Wo3, const float* bo3,
    float* out) {
  __shared__ float attr[16][512];
  __shared__ float o1[16][128];
  __shared__ float o2[16][128];
  int t = threadIdx.x;
  for (int i = t; i < 4096; i += 256) {
    int g = i >> 8, c = i & 255;
    float vn = gn_acc[i] / (float)max(cnt_n[g], 1);
    float ve = ge_acc[i] / (float)max(cnt_e[g], 1);
    out[i] = vn;
    out[4096 + i] = ve;
    attr[g][c] = vn;
    attr[g][256 + c] = ve;
  }
  __syncthreads();
  {
    int j = t & 127, gh = t >> 7;
    float a[8];
#pragma unroll
    for (int q = 0; q < 8; q++) a[q] = bo1[j];
    for (int k = 0; k < 512; k++) {
      float w = Wo1[k * 128 + j];
#pragma unroll
      for (int q = 0; q < 8; q++) a[q] = fmaf(attr[gh * 8 + q][k], w, a[q]);
    }
#pragma unroll
    for (int q = 0; q < 8; q++) o1[gh * 8 + q][j] = fmaxf(a[q], 0.f);
  }
  __syncthreads();
  {
    int j = t & 127, gh = t >> 7;
    float a[8];
#pragma unroll
    for (int q = 0; q < 8; q++) a[q] = bo2[j];
    for (int k = 0; k < 128; k++) {
      float w = Wo2[k * 128 + j];
#pragma unroll
      for (int q = 0; q < 8; q++) a[q] = fmaf(o1[gh * 8 + q][k], w, a[q]);
    }
#pragma unroll
    for (int q = 0; q < 8; q++) o2[gh * 8 + q][j] = fmaxf(a[q], 0.f);
  }
  __syncthreads();
  {
    int j = t & 31, gb = t >> 5;
#pragma unroll
    for (int q = 0; q < 2; q++) {
      int g = gb * 2 + q;
      float a = bo3[j];
      for (int k = 0; k < 128; k++) a = fmaf(o2[g][k], Wo3[k * 32 + j], a);
      out[8192 + g * 32 + j] = a;
    }
  }
}

extern "C" void kernel_launch(void* const* d_in, const int* in_sizes, int n_in,
                              void* d_out, int out_size, void* d_ws, size_t ws_size,
                              hipStream_t stream) {
  float* ea = (float*)d_in[1];               // [NE,64] f32, updated IN-PLACE
  const int* edge_index = (const int*)d_in[3];
  const int* row = edge_index;
  const int* col = edge_index + NE;
  const int* batch = (const int*)d_in[4];
  const int* ebatch = (const int*)d_in[5];
  const float* W1s = (const float*)d_in[6];  // [3,128,128]
  const float* b1s = (const float*)d_in[7];  // [3,128]
  const float* W2s = (const float*)d_in[8];  // [3,128,64]
  const float* b2s = (const float*)d_in[9];  // [3,64]
  const float* Wo1 = (const float*)d_in[10];
  const float* bo1 = (const float*)d_in[11];
  const float* Wo2 = (const float*)d_in[12];
  const float* bo2 = (const float*)d_in[13];
  const float* Wo3 = (const float*)d_in[14];
  const float* bo3 = (const float*)d_in[15];

  char* p = (char*)d_ws;
  auto alloc = [&](size_t b) { char* r = p; p += (b + 255) & ~(size_t)255; return r; };
  // ---- zero region (one memset) ----
  int* deg = (int*)alloc(NN * 4);
  int* cursor = (int*)alloc(NN * 4);
  int* cnt_n = (int*)alloc(64);
  int* cnt_e = (int*)alloc(64);
  float* gn_acc = (float*)alloc(NGR * 256 * 4);
  float* ge_acc = (float*)alloc(NGR * 256 * 4);
  size_t zbytes = (size_t)(p - (char*)d_ws);
  // ---- non-zeroed ----
  int* csr_off = (int*)alloc((NN + 1) * 4);
  int* csr_eid = (int*)alloc((size_t)NE * 4);
  float* hbuf = (float*)alloc((size_t)NN * 64 * 4);
  u16* W1T = (u16*)alloc(3 * 128 * 128 * 2);
  u16* W2T = (u16*)alloc(3 * 64 * 128 * 2);

  hipMemsetAsync(d_ws, 0, zbytes, stream);

  prep_w_k<<<(3 * 128 * 128 + 3 * 128 * 64 + 255) / 256, 256, 0, stream>>>(W1s, W2s, W1T, W2T);
  hist_deg<<<(NE + 255) / 256, 256, 0, stream>>>(col, deg);
  count_graphs<<<1, 64, 0, stream>>>(batch, ebatch, cnt_n, cnt_e);
  scan_deg<<<1, 256, 0, stream>>>(deg, csr_off);
  fill_csr<<<(NE + 255) / 256, 256, 0, stream>>>(col, csr_off, cursor, csr_eid);

  // layer-0 pools on raw edge_attr
  pool_edges_k<<<2048, 256, 0, stream>>>(ea, ebatch, ge_acc, 0);
  gather_k<<<1024, 256, 0, stream>>>(ea, csr_off, csr_eid, batch, hbuf, gn_acc, 0, 1);

  for (int l = 0; l < 3; l++) {
    mlp_mfma_k<<<NE / 64, 256, 0, stream>>>(hbuf, ea, row,
        W1T + l * 16384, b1s + l * 128, W2T + l * 8192, b2s + l * 64,
        ebatch, ge_acc, (l + 1) * 64);
    gather_k<<<1024, 256, 0, stream>>>(ea, csr_off, csr_eid, batch, hbuf,
                                       gn_acc, (l + 1) * 64, l < 2 ? 1 : 0);
  }

  finalize_k<<<1, 256, 0, stream>>>(gn_acc, ge_acc, cnt_n, cnt_e,
      Wo1, bo1, Wo2, bo2, Wo3, bo3, (float*)d_out);
}

// Round 2
// 2258.808 us; speedup vs baseline: 1.8425x; 1.8425x over previous
//
#include <hip/hip_runtime.h>

#define NN 50000      // nodes
#define NE 800000     // edges
#define NGR 16        // graphs

typedef unsigned short u16;
typedef unsigned int u32;
typedef __attribute__((ext_vector_type(8))) short bf16x8;
typedef __attribute__((ext_vector_type(4))) float f32x4;

__device__ __forceinline__ u16 f2bf(float f) {       // RNE f32->bf16
  u32 u = __float_as_uint(f);
  return (u16)((u + 0x7fffu + ((u >> 16) & 1u)) >> 16);
}

// ---------- degree histogram ----------
__global__ void hist_deg(const int* col, int* deg) {
  int e = blockIdx.x * blockDim.x + threadIdx.x;
  if (e < NE) atomicAdd(&deg[col[e]], 1);
}

// ---------- per-graph counts (sorted ids) ----------
__device__ int lbound(const int* a, int n, int v) {
  int lo = 0, hi = n;
  while (lo < hi) { int m = (lo + hi) >> 1; if (a[m] < v) lo = m + 1; else hi = m; }
  return lo;
}
__global__ void count_graphs(const int* batch, const int* ebatch, int* cnt_n, int* cnt_e) {
  int t = threadIdx.x;
  if (t < NGR) cnt_n[t] = lbound(batch, NN, t + 1) - lbound(batch, NN, t);
  else if (t < 2 * NGR) { int g = t - NGR; cnt_e[g] = lbound(ebatch, NE, g + 1) - lbound(ebatch, NE, g); }
}

// ---------- exclusive scan of deg -> csr_off (single block) ----------
__global__ __launch_bounds__(256) void scan_deg(const int* deg, int* off) {
  __shared__ int sums[256];
  const int CH = (NN + 255) / 256;
  int t = threadIdx.x;
  int base = t * CH;
  int s = 0;
  for (int i = 0; i < CH; i++) { int idx = base + i; if (idx < NN) s += deg[idx]; }
  sums[t] = s;
  __syncthreads();
  for (int d = 1; d < 256; d <<= 1) {
    int v = (t >= d) ? sums[t - d] : 0;
    __syncthreads();
    sums[t] += v;
    __syncthreads();
  }
  int run = (t == 0) ? 0 : sums[t - 1];
  for (int i = 0; i < CH; i++) { int idx = base + i; if (idx < NN) { off[idx] = run; run += deg[idx]; } }
  if (t == 255) off[NN] = run;
}

// ---------- CSR fill ----------
__global__ void fill_csr(const int* col, const int* off, int* cursor, int* eid) {
  int e = blockIdx.x * blockDim.x + threadIdx.x;
  if (e < NE) {
    int c = col[e];
    int p = atomicAdd(&cursor[c], 1);
    eid[off[c] + p] = e;
  }
}

// ---------- weights f32 -> bf16 TRANSPOSED (W1T[l][n][k], W2T[l][n][k]) ----------
__global__ void prep_w_k(const float* W1, const float* W2, u16* W1T, u16* W2T) {
  int i = blockIdx.x * 256 + threadIdx.x;
  if (i < 3 * 128 * 128) {
    int l = i / 16384, k = (i >> 7) & 127, n = i & 127;
    W1T[l * 16384 + n * 128 + k] = f2bf(W1[i]);
  } else {
    int j = i - 3 * 128 * 128;
    if (j < 3 * 128 * 64) {
      int l = j / 8192, k = (j >> 6) & 127, n = j & 63;
      W2T[l * 8192 + n * 128 + k] = f2bf(W2[j]);
    }
  }
}

// ---------- layer-0 pool: ea rows [NE,64] by sorted ebatch -> gacc[g*256 + loff + d] ----------
// float4 per lane (16B), 4 row-slots per wave, per-slot run tracking of graph id.
__global__ __launch_bounds__(256) void pool_edges_k(const float* ea, const int* ebatch,
                                                    float* gacc, int loff) {
  int gid = blockIdx.x * blockDim.x + threadIdx.x;
  int w = gid >> 6, lane = gid & 63;
  const int NW = (gridDim.x * blockDim.x) >> 6;
  const int CH = (((NE / 4) + NW - 1) / NW) * 4;     // rows per wave, multiple of 4
  int r0 = w * CH, r1 = min(r0 + CH, NE);
  if (r0 >= r1) return;
  int q = lane >> 4;          // row slot 0..3
  int c4 = (lane & 15) * 4;   // column base
  float4 acc = {0.f, 0.f, 0.f, 0.f};
  int cg = ebatch[r0 + q];
  for (int r = r0; r < r1; r += 4) {
    int rr = r + q;           // r1,r0 multiples of 4 -> rr < r1 <= NE
    int g = ebatch[rr];
    if (g != cg) {
      float* dst = gacc + cg * 256 + loff + c4;
      atomicAdd(dst + 0, acc.x); atomicAdd(dst + 1, acc.y);
      atomicAdd(dst + 2, acc.z); atomicAdd(dst + 3, acc.w);
      acc = {0.f, 0.f, 0.f, 0.f};
      cg = g;
    }
    float4 v = *(const float4*)(ea + (size_t)rr * 64 + c4);
    acc.x += v.x; acc.y += v.y; acc.z += v.z; acc.w += v.w;
  }
  float* dst = gacc + cg * 256 + loff + c4;
  atomicAdd(dst + 0, acc.x); atomicAdd(dst + 1, acc.y);
  atomicAdd(dst + 2, acc.z); atomicAdd(dst + 3, acc.w);
}

// ---------- h = CSR gather-mean of ea; pool h by batch -> gacc[g*256+loff+d] ----------
// One full wave per row-load (64 lanes x 4B = 256B coalesced), 4-edge manual
// unroll -> 4 independent 256B loads in flight per wave (MLP is the currency
// for random gathers). Grid 2048 blocks = 8192 waves (~32/CU) for TLP.
__global__ __launch_bounds__(256) void gather_k(const float* ea, const int* off, const int* eid,
                                                const int* batch, float* hbuf, float* gacc,
                                                int loff, int store_h) {
  int gid = blockIdx.x * blockDim.x + threadIdx.x;
  int w = gid >> 6, lane = gid & 63;
  int nw = (gridDim.x * blockDim.x) >> 6;
  const float* base = ea + lane;
  for (int n = w; n < NN; n += nw) {
    int s = off[n], e = off[n + 1];
    int g = batch[n];
    float a0 = 0.f, a1 = 0.f, a2 = 0.f, a3 = 0.f;
    int i = s;
    for (; i + 4 <= e; i += 4) {
      int e0 = eid[i], e1 = eid[i + 1], e2 = eid[i + 2], e3 = eid[i + 3];
      a0 += base[(size_t)e0 * 64];
      a1 += base[(size_t)e1 * 64];
      a2 += base[(size_t)e2 * 64];
      a3 += base[(size_t)e3 * 64];
    }
    for (; i < e; i++) a0 += base[(size_t)eid[i] * 64];
    float acc = (a0 + a1) + (a2 + a3);
    float hv = acc / (float)max(e - s, 1);
    if (store_h) hbuf[(size_t)n * 64 + lane] = hv;
    atomicAdd(&gacc[g * 256 + loff + lane], hv);
  }
}

// ---------- edge MLP via bf16 MFMA: ea = relu([h[row],ea]@W1+b1)@W2+b2, in-place ----------
// Block = 256 thr (4 waves), 64 edges. Fused ge-pool epilogue (ebatch sorted ->
// block is single-graph except <=15 boundary blocks).
__global__ __launch_bounds__(256) void mlp_mfma_k(
    const float* hbuf, float* ea, const int* rowp,
    const u16* W1T, const float* b1,     // W1T [128n][128k] bf16
    const u16* W2T, const float* b2,     // W2T [64n][128k] bf16
    const int* ebatch, float* gacc, int loff) {
  __shared__ u16 sh[2 * 64 * 136];       // xin | hid
  u16* xin = sh;
  u16* hid = sh + 64 * 136;
  const int t = threadIdx.x;
  const int e0 = blockIdx.x * 64;
  const int lane = t & 63;
  const int wave = t >> 6;
  const int m16 = lane & 15;             // fragment row/col index
  const int quad = lane >> 4;            // k-subblock

  // ---- preload B fragments (registers, straight from global; L2-hot) ----
  bf16x8 B1[2][4], B2[4];
#pragma unroll
  for (int ni = 0; ni < 2; ni++)
#pragma unroll
    for (int ki = 0; ki < 4; ki++)
      B1[ni][ki] = *(const bf16x8*)(W1T + (wave * 32 + ni * 16 + m16) * 128 + ki * 32 + quad * 8);
#pragma unroll
  for (int ki = 0; ki < 4; ki++)
    B2[ki] = *(const bf16x8*)(W2T + (wave * 16 + m16) * 128 + ki * 32 + quad * 8);

  // ---- stage xin[64][128] = [h[row[e]], ea[e]] as bf16 ----
#pragma unroll
  for (int it = 0; it < 8; it++) {
    int f = it * 256 + t;                // float4 id 0..2047
    int r = f >> 5;                      // edge row 0..63
    int c = (f & 31) * 4;                // col 0..124
    const float* src;
    if (c < 64) {
      int nd = rowp[e0 + r];
      src = hbuf + (size_t)nd * 64 + c;
    } else {
      src = ea + (size_t)(e0 + r) * 64 + (c - 64);
    }
    float4 v = *(const float4*)src;
    u32 p0 = (u32)f2bf(v.x) | ((u32)f2bf(v.y) << 16);
    u32 p1 = (u32)f2bf(v.z) | ((u32)f2bf(v.w) << 16);
    u32* dst = (u32*)&xin[r * 136 + c];
    dst[0] = p0;
    dst[1] = p1;
  }
  __syncthreads();

  // ---- GEMM1: [64x128] @ W1[128x128] -> hid, +bias, ReLU ----
  f32x4 zero = {0.f, 0.f, 0.f, 0.f};
  f32x4 acc1[2][4];
#pragma unroll
  for (int ni = 0; ni < 2; ni++)
#pragma unroll
    for (int mi = 0; mi < 4; mi++) acc1[ni][mi] = zero;

#pragma unroll
  for (int ki = 0; ki < 4; ki++) {
#pragma unroll
    for (int mi = 0; mi < 4; mi++) {
      bf16x8 A = *(const bf16x8*)&xin[(mi * 16 + m16) * 136 + ki * 32 + quad * 8];
      acc1[0][mi] = __builtin_amdgcn_mfma_f32_16x16x32_bf16(A, B1[0][ki], acc1[0][mi], 0, 0, 0);
      acc1[1][mi] = __builtin_amdgcn_mfma_f32_16x16x32_bf16(A, B1[1][ki], acc1[1][mi], 0, 0, 0);
    }
  }
  float b1v0 = b1[wave * 32 + m16];
  float b1v1 = b1[wave * 32 + 16 + m16];
#pragma unroll
  for (int mi = 0; mi < 4; mi++) {
#pragma unroll
    for (int reg = 0; reg < 4; reg++) {
      int r = mi * 16 + quad * 4 + reg;
      hid[r * 136 + wave * 32 + m16]      = f2bf(fmaxf(acc1[0][mi][reg] + b1v0, 0.f));
      hid[r * 136 + wave * 32 + 16 + m16] = f2bf(fmaxf(acc1[1][mi][reg] + b1v1, 0.f));
    }
  }
  __syncthreads();

  // ---- GEMM2: hid[64x128] @ W2[128x64] -> ea rows (in-place), +bias ----
  f32x4 acc2[4];
#pragma unroll
  for (int mi = 0; mi < 4; mi++) acc2[mi] = zero;
#pragma unroll
  for (int ki = 0; ki < 4; ki++) {
#pragma unroll
    for (int mi = 0; mi < 4; mi++) {
      bf16x8 A = *(const bf16x8*)&hid[(mi * 16 + m16) * 136 + ki * 32 + quad * 8];
      acc2[mi] = __builtin_amdgcn_mfma_f32_16x16x32_bf16(A, B2[ki], acc2[mi], 0, 0, 0);
    }
  }
  float b2v = b2[wave * 16 + m16];
#pragma unroll
  for (int mi = 0; mi < 4; mi++) {
#pragma unroll
    for (int reg = 0; reg < 4; reg++) {
      int r = mi * 16 + quad * 4 + reg;
      ea[(size_t)(e0 + r) * 64 + wave * 16 + m16] = acc2[mi][reg] + b2v;
    }
  }

  // ---- fused ge pooling: sum this block's 64 output rows per graph ----
  int g0 = ebatch[e0], g1 = ebatch[e0 + 63];
  int colo = wave * 16 + m16;
  if (g0 == g1) {                        // fast path: single-graph block
    float s = 0.f;
#pragma unroll
    for (int mi = 0; mi < 4; mi++)
#pragma unroll
      for (int reg = 0; reg < 4; reg++) s += acc2[mi][reg] + b2v;
    s += __shfl_xor(s, 16);
    s += __shfl_xor(s, 32);
    if (quad == 0) atomicAdd(&gacc[g0 * 256 + loff + colo], s);
  } else {                               // boundary block (<=15 total): per-value atomics
#pragma unroll
    for (int mi = 0; mi < 4; mi++)
#pragma unroll
      for (int reg = 0; reg < 4; reg++) {
        int r = mi * 16 + quad * 4 + reg;
        atomicAdd(&gacc[ebatch[e0 + r] * 256 + loff + colo], acc2[mi][reg] + b2v);
      }
  }
}

// ---------- finalize: means (acc already in output layout), head, f32 out ----------
__global__ __launch_bounds__(256) void finalize_k(
    const float* gn_acc, const float* ge_acc,
    const int* cnt_n, const int* cnt_e,
    const float* Wo1, const float* bo1,
    const float* Wo2, const float* bo2,
    const float* Wo3, const float* bo3,
    float* out) {
  __shared__ float attr[16][512];
  __shared__ float o1[16][128];
  __shared__ float o2[16][128];
  int t = threadIdx.x;
  for (int i = t; i < 4096; i += 256) {
    int g = i >> 8, c = i & 255;
    float vn = gn_acc[i] / (float)max(cnt_n[g], 1);
    float ve = ge_acc[i] / (float)max(cnt_e[g], 1);
    out[i] = vn;
    out[4096 + i] = ve;
    attr[g][c] = vn;
    attr[g][256 + c] = ve;
  }
  __syncthreads();
  {
    int j = t & 127, gh = t >> 7;
    float a[8];
#pragma unroll
    for (int q = 0; q < 8; q++) a[q] = bo1[j];
    for (int k = 0; k < 512; k++) {
      float w = Wo1[k * 128 + j];
#pragma unroll
      for (int q = 0; q < 8; q++) a[q] = fmaf(attr[gh * 8 + q][k], w, a[q]);
    }
#pragma unroll
    for (int q = 0; q < 8; q++) o1[gh * 8 + q][j] = fmaxf(a[q], 0.f);
  }
  __syncthreads();
  {
    int j = t & 127, gh = t >> 7;
    float a[8];
#pragma unroll
    for (int q = 0; q < 8; q++) a[q] = bo2[j];
    for (int k = 0; k < 128; k++) {
      float w = Wo2[k * 128 + j];
#pragma unroll
      for (int q = 0; q < 8; q++) a[q] = fmaf(o1[gh * 8 + q][k], w, a[q]);
    }
#pragma unroll
    for (int q = 0; q < 8; q++) o2[gh * 8 + q][j] = fmaxf(a[q], 0.f);
  }
  __syncthreads();
  {
    int j = t & 31, gb = t >> 5;
#pragma unroll
    for (int q = 0; q < 2; q++) {
      int g = gb * 2 + q;
      float a = bo3[j];
      for (int k = 0; k < 128; k++) a = fmaf(o2[g][k], Wo3[k * 32 + j], a);
      out[8192 + g * 32 + j] = a;
    }
  }
}

extern "C" void kernel_launch(void* const* d_in, const int* in_sizes, int n_in,
                              void* d_out, int out_size, void* d_ws, size_t ws_size,
                              hipStream_t stream) {
  float* ea = (float*)d_in[1];               // [NE,64] f32, updated IN-PLACE
  const int* edge_index = (const int*)d_in[3];
  const int* row = edge_index;
  const int* col = edge_index + NE;
  const int* batch = (const int*)d_in[4];
  const int* ebatch = (const int*)d_in[5];
  const float* W1s = (const float*)d_in[6];  // [3,128,128]
  const float* b1s = (const float*)d_in[7];  // [3,128]
  const float* W2s = (const float*)d_in[8];  // [3,128,64]
  const float* b2s = (const float*)d_in[9];  // [3,64]
  const float* Wo1 = (const float*)d_in[10];
  const float* bo1 = (const float*)d_in[11];
  const float* Wo2 = (const float*)d_in[12];
  const float* bo2 = (const float*)d_in[13];
  const float* Wo3 = (const float*)d_in[14];
  const float* bo3 = (const float*)d_in[15];

  char* p = (char*)d_ws;
  auto alloc = [&](size_t b) { char* r = p; p += (b + 255) & ~(size_t)255; return r; };
  // ---- zero region (one memset) ----
  int* deg = (int*)alloc(NN * 4);
  int* cursor = (int*)alloc(NN * 4);
  int* cnt_n = (int*)alloc(64);
  int* cnt_e = (int*)alloc(64);
  float* gn_acc = (float*)alloc(NGR * 256 * 4);
  float* ge_acc = (float*)alloc(NGR * 256 * 4);
  size_t zbytes = (size_t)(p - (char*)d_ws);
  // ---- non-zeroed ----
  int* csr_off = (int*)alloc((NN + 1) * 4);
  int* csr_eid = (int*)alloc((size_t)NE * 4);
  float* hbuf = (float*)alloc((size_t)NN * 64 * 4);
  u16* W1T = (u16*)alloc(3 * 128 * 128 * 2);
  u16* W2T = (u16*)alloc(3 * 64 * 128 * 2);

  hipMemsetAsync(d_ws, 0, zbytes, stream);

  prep_w_k<<<(3 * 128 * 128 + 3 * 128 * 64 + 255) / 256, 256, 0, stream>>>(W1s, W2s, W1T, W2T);
  hist_deg<<<(NE + 255) / 256, 256, 0, stream>>>(col, deg);
  count_graphs<<<1, 64, 0, stream>>>(batch, ebatch, cnt_n, cnt_e);
  scan_deg<<<1, 256, 0, stream>>>(deg, csr_off);
  fill_csr<<<(NE + 255) / 256, 256, 0, stream>>>(col, csr_off, cursor, csr_eid);

  // layer-0 pools on raw edge_attr
  pool_edges_k<<<2048, 256, 0, stream>>>(ea, ebatch, ge_acc, 0);
  gather_k<<<2048, 256, 0, stream>>>(ea, csr_off, csr_eid, batch, hbuf, gn_acc, 0, 1);

  for (int l = 0; l < 3; l++) {
    mlp_mfma_k<<<NE / 64, 256, 0, stream>>>(hbuf, ea, row,
        W1T + l * 16384, b1s + l * 128, W2T + l * 8192, b2s + l * 64,
        ebatch, ge_acc, (l + 1) * 64);
    gather_k<<<2048, 256, 0, stream>>>(ea, csr_off, csr_eid, batch, hbuf,
                                       gn_acc, (l + 1) * 64, l < 2 ? 1 : 0);
  }

  finalize_k<<<1, 256, 0, stream>>>(gn_acc, ge_acc, cnt_n, cnt_e,
      Wo1, bo1, Wo2, bo2, Wo3, bo3, (float*)d_out);
}